// Round 12
// baseline (1868.296 us; speedup 1.0000x reference)
//
#include <hip/hip_runtime.h>
#include <hip/hip_bf16.h>
#include <math.h>

typedef __bf16 bf16_t;
typedef __bf16 bf16x4 __attribute__((ext_vector_type(4)));
typedef __bf16 bf16x8 __attribute__((ext_vector_type(8)));
typedef float  f32x4  __attribute__((ext_vector_type(4)));
typedef float  f32x16 __attribute__((ext_vector_type(16)));

#define AS1 __attribute__((address_space(1)))
#define AS3 __attribute__((address_space(3)))

__device__ __forceinline__ void gload_lds16(const bf16_t* g, char* l) {
  __builtin_amdgcn_global_load_lds((const AS1 void*)g, (AS3 void*)l, 16, 0, 0);
}

static constexpr int N_ROWS = 8192;
static constexpr int DDIM   = 4096;
static constexpr int KEXP   = 8;
static constexpr int FHID   = 1024;
static constexpr int KD     = 8192;   // inner dim of both GEMMs (2D and K*F)
static constexpr int NKT    = KD / 64; // 128 k-tiles

// ================= packed fragment-major tile format (r10, verified) =================
// Per (256-row block, 64-k tile): 32 KB contiguous; byte layout == GEMM LDS layout.
// A: (R>>7)*16384 + ((k>>4)&3)*4096 + ((R>>5)&3)*1024 + ((k>>3)&1)*512 + (R&31)*16 + (k&7)*2
// B: ((k>>4)&3)*8192 + ((C>>5)&7)*1024 + ((k>>3)&1)*512 + (C&31)*16 + (k&7)*2
// MFMA 32x32x16 operand: lane l = row/col l&31, k-half l>>5 -> lane*16 within 1KB block.

// ---------------- routing: weights = softmax(h_mask @ Wr^T + br) ----------------
__global__ __launch_bounds__(256)
void routing_kernel(const float* __restrict__ hm, const float* __restrict__ Wr,
                    const float* __restrict__ br, float* __restrict__ wgt) {
  const int n = blockIdx.x;
  const int t = threadIdx.x;
  const int wid = t >> 6;
  const float4* row = (const float4*)(hm + (size_t)n * DDIM);
  float4 x[4];
#pragma unroll
  for (int j = 0; j < 4; ++j) x[j] = row[t + j * 256];
  __shared__ float red[KEXP][4];
  float part[KEXP];
#pragma unroll
  for (int k = 0; k < KEXP; ++k) {
    const float4* wr = (const float4*)(Wr + (size_t)k * DDIM);
    float s = 0.f;
#pragma unroll
    for (int j = 0; j < 4; ++j) {
      float4 w4 = wr[t + j * 256];
      s += x[j].x * w4.x + x[j].y * w4.y + x[j].z * w4.z + x[j].w * w4.w;
    }
#pragma unroll
    for (int off = 32; off > 0; off >>= 1) s += __shfl_down(s, off);
    part[k] = s;
  }
  if ((t & 63) == 0) {
#pragma unroll
    for (int k = 0; k < KEXP; ++k) red[k][wid] = part[k];
  }
  __syncthreads();
  if (t == 0) {
    float lg[KEXP];
    float mx = -1e30f;
#pragma unroll
    for (int k = 0; k < KEXP; ++k) {
      lg[k] = red[k][0] + red[k][1] + red[k][2] + red[k][3] + br[k];
      mx = fmaxf(mx, lg[k]);
    }
    float sum = 0.f;
#pragma unroll
    for (int k = 0; k < KEXP; ++k) { lg[k] = expf(lg[k] - mx); sum += lg[k]; }
    float inv = 1.f / sum;
#pragma unroll
    for (int k = 0; k < KEXP; ++k) wgt[(size_t)n * KEXP + k] = lg[k] * inv;
  }
}

// ---------------- pack kernels: fp32 source -> bf16 packed tiles (r10) ----------------
__device__ __forceinline__ bf16x4 cvt4(float4 v) {
  bf16x4 o;
  o[0] = (bf16_t)v.x; o[1] = (bf16_t)v.y; o[2] = (bf16_t)v.z; o[3] = (bf16_t)v.w;
  return o;
}

__global__ __launch_bounds__(256)
void pack_cond_kernel(const float* __restrict__ ha, const float* __restrict__ hm,
                      bf16_t* __restrict__ Apk) {
  const int bm = blockIdx.x >> 7, t = blockIdx.x & 127;
  const int tid = threadIdx.x;
  const float* src = (t < 64) ? ha : hm;
  const int cb = (t & 63) * 64;
  __shared__ char pb[32768];
#pragma unroll
  for (int i = 0; i < 16; ++i) {
    int u = i * 256 + tid;
    int r = u >> 4, c = (u & 15) * 4;
    float4 v = *(const float4*)(src + (size_t)(bm * 256 + r) * DDIM + cb + c);
    int off = ((r >> 7) & 1) * 16384 + ((c >> 4) & 3) * 4096 + ((r >> 5) & 3) * 1024
            + ((c >> 3) & 1) * 512 + (r & 31) * 16 + (c & 7) * 2;
    *(bf16x4*)(pb + off) = cvt4(v);
  }
  __syncthreads();
  char* dst = (char*)Apk + (size_t)blockIdx.x * 32768;
#pragma unroll
  for (int i = 0; i < 8; ++i) {
    int off = i * 4096 + tid * 16;
    *(float4*)(dst + off) = *(const float4*)(pb + off);
  }
}

__global__ __launch_bounds__(256)
void pack_w1_kernel(const float* __restrict__ W1, bf16_t* __restrict__ Bpk) {
  const int bn = blockIdx.x >> 7, t = blockIdx.x & 127;
  const int tid = threadIdx.x;
  __shared__ char pb[32768];
#pragma unroll
  for (int i = 0; i < 16; ++i) {
    int u = i * 256 + tid;
    int r = u >> 4, c = (u & 15) * 4;
    float4 v = *(const float4*)(W1 + (size_t)(bn * 256 + r) * KD + t * 64 + c);
    int off = ((c >> 4) & 3) * 8192 + ((r >> 5) & 7) * 1024
            + ((c >> 3) & 1) * 512 + (r & 31) * 16 + (c & 7) * 2;
    *(bf16x4*)(pb + off) = cvt4(v);
  }
  __syncthreads();
  char* dst = (char*)Bpk + (size_t)blockIdx.x * 32768;
#pragma unroll
  for (int i = 0; i < 8; ++i) {
    int off = i * 4096 + tid * 16;
    *(float4*)(dst + off) = *(const float4*)(pb + off);
  }
}

__global__ __launch_bounds__(256)
void pack_w2_kernel(const float* __restrict__ W2, bf16_t* __restrict__ Bpk) {
  const int bn = blockIdx.x >> 7, t = blockIdx.x & 127;
  const int tid = threadIdx.x;
  const int ke = t >> 4, f0 = (t & 15) * 64;
  __shared__ char pb[32768];
#pragma unroll
  for (int i = 0; i < 16; ++i) {
    int u = i * 256 + tid;
    int r = u >> 4, c = (u & 15) * 4;
    float4 v = *(const float4*)(W2 + ((size_t)ke * DDIM + bn * 256 + r) * FHID + f0 + c);
    int off = ((c >> 4) & 3) * 8192 + ((r >> 5) & 7) * 1024
            + ((c >> 3) & 1) * 512 + (r & 31) * 16 + (c & 7) * 2;
    *(bf16x4*)(pb + off) = cvt4(v);
  }
  __syncthreads();
  char* dst = (char*)Bpk + (size_t)blockIdx.x * 32768;
#pragma unroll
  for (int i = 0; i < 8; ++i) {
    int off = i * 4096 + tid * 16;
    *(float4*)(dst + off) = *(const float4*)(pb + off);
  }
}

// ---------------- 256x256 GEMM v12: A via LDS, B streamed through registers --------
// 8 waves (2Mx4N), per-wave 128x64, 32x32x16 MFMA, acc[4][2] f32x16 (128 VGPR).
// LDS carries ONLY A: 2 buffers x 32 KB. Per k-step per CU: LDS 32 KB reads +
// 8 KB writes (~470cy) < MFMA 517cy -> MFMA-bound (r8/r10 carried 48+16 KB -> wall).
// B: coalesced 1KB global_load_dwordx4 per fragment (packed format), issued 2
// k-steps (~1030cy) ahead into named regs b{0..3}{x,y} (rule #20), consumed by MFMA
// directly; 2x cross-wave redundancy -> 16 KB/k-step/CU from L2 (32 B/cy < ~56 budget).
// Compiler's fine-grained vmcnt/lgkm insertion handles B/aq readiness; manual asm
// only for the staging gate: per tile VM issue order is
//   st0,st1,B(t,s2)x2, st2,st3,B(t,s3)x2, B(t+1,s0)x2, B(t+1,s1)x2   (12 ops)
// -> vmcnt(6) at tile end retires all 4 A-stages (6 B-loads follow the last stage),
// then ONE s_barrier publishes the next buffer. Buffer audit: stages target the
// opposite buffer; all waves' reads of it retired before the barrier they passed;
// B is register-only (no LDS races). Modular tau wrap keeps counts uniform.
// MODE 1: +b1, exact GELU, *w[n][expert], store bf16 PACKED (Hpk = GEMM2's A)
// MODE 2: + sum_k w[n][k]*b2[k][col], store fp32 row-major (out)
template <int MODE, int NCOLS>
__global__ __launch_bounds__(512, 2)
void gemm256_kernel(const bf16_t* __restrict__ Apk, const bf16_t* __restrict__ Bpk,
                    void* __restrict__ Cout, const float* __restrict__ bias,
                    const float* __restrict__ wgt) {
  __shared__ char lds_raw[2 * 32768];    // A only, 64 KB

  const int tid  = threadIdx.x;
  const int wid  = tid >> 6;             // 0..7
  const int lane = tid & 63;
  const int wr   = wid >> 2;             // 0..1  (M half)
  const int wc   = wid & 3;              // 0..3  (N quarter)

  // ---- 2-D concurrency-window block remap (16x16 window, 4x8 per XCD)
  constexpr int NBN    = NCOLS / 256;    // 32 (GEMM1) or 16 (GEMM2)
  constexpr int NWIN_N = NBN / 16;       // 2 or 1
  const int bid = blockIdx.x;
  const int w   = bid >> 8;
  const int sl  = bid & 255;
  const int xcd = sl & 7;
  const int cu  = sl >> 3;
  const int wm  = w / NWIN_N, wn = w % NWIN_N;
  const int bm  = wm * 16 + ((xcd >> 1) << 2) + (cu & 3);
  const int bn  = wn * 16 + ((xcd & 1) << 3) + (cu >> 2);
  const int arow0 = bm * 256;
  const int brow0 = bn * 256;

  const char* Ab = (const char*)Apk + (size_t)bm * NKT * 32768;
  const char* Bb = (const char*)Bpk + (size_t)bn * NKT * 32768;

  // staging: wave wid owns chunks c0..c0+3 (1 KB each); LDS dst wave-uniform
  const int c0 = wid * 4;
  // B fragment byte offset within an s-block: colgroups {2wc, 2wc+1}
  const int bcg = wc * 2048 + lane * 16;
  // A read base within buffer: wr half + lane*16
  const char* bA0 = lds_raw + wr * 16384 + lane * 16;
  const char* bA1 = bA0 + 32768;

  f32x16 acc[4][2];
#pragma unroll
  for (int mi = 0; mi < 4; ++mi)
#pragma unroll
    for (int nj = 0; nj < 2; ++nj)
#pragma unroll
      for (int r = 0; r < 16; ++r) acc[mi][nj][r] = 0.f;

  bf16x8 b0x, b0y, b1x, b1y, b2x, b2y, b3x, b3y;

#define SB __builtin_amdgcn_sched_barrier(0);
#define STG(I, TAU, NB)                                                          \
  gload_lds16((const bf16_t*)(Ab + (size_t)((TAU) & (NKT - 1)) * 32768 +         \
                              (c0 + (I)) * 1024 + lane * 16),                    \
              (NB) + (c0 + (I)) * 1024);
#define LDB(VAR, TAU, S, NJ)                                                     \
  VAR = *(const bf16x8*)(Bb + (size_t)((TAU) & (NKT - 1)) * 32768 +              \
                         (S) * 8192 + bcg + (NJ) * 1024);

#define KSTEP(PA, BX, BY)                                                        \
  {                                                                              \
    bf16x8 aq0, aq1, aq2, aq3;                                                   \
    aq0 = *(const bf16x8*)(PA);          SB                                      \
    aq1 = *(const bf16x8*)((PA) + 1024); SB                                      \
    aq2 = *(const bf16x8*)((PA) + 2048); SB                                      \
    aq3 = *(const bf16x8*)((PA) + 3072); SB                                      \
    __builtin_amdgcn_s_setprio(1);                                               \
    acc[0][0] = __builtin_amdgcn_mfma_f32_32x32x16_bf16(aq0, BX, acc[0][0], 0, 0, 0); \
    acc[0][1] = __builtin_amdgcn_mfma_f32_32x32x16_bf16(aq0, BY, acc[0][1], 0, 0, 0); \
    SB                                                                           \
    acc[1][0] = __builtin_amdgcn_mfma_f32_32x32x16_bf16(aq1, BX, acc[1][0], 0, 0, 0); \
    acc[1][1] = __builtin_amdgcn_mfma_f32_32x32x16_bf16(aq1, BY, acc[1][1], 0, 0, 0); \
    SB                                                                           \
    acc[2][0] = __builtin_amdgcn_mfma_f32_32x32x16_bf16(aq2, BX, acc[2][0], 0, 0, 0); \
    acc[2][1] = __builtin_amdgcn_mfma_f32_32x32x16_bf16(aq2, BY, acc[2][1], 0, 0, 0); \
    SB                                                                           \
    acc[3][0] = __builtin_amdgcn_mfma_f32_32x32x16_bf16(aq3, BX, acc[3][0], 0, 0, 0); \
    acc[3][1] = __builtin_amdgcn_mfma_f32_32x32x16_bf16(aq3, BY, acc[3][1], 0, 0, 0); \
    SB                                                                           \
    __builtin_amdgcn_s_setprio(0);                                               \
  }

// One K-tile. VM issue order (per wave): st0,st1,B(t,s2)x2 | st2,st3,B(t,s3)x2 |
// B(t+1,s0)x2 | B(t+1,s1)x2 -> gate vmcnt(6) retires all stages; 1 barrier.
#define TILE(T, BA, NB)                                                          \
  STG(0, (T) + 1, NB) STG(1, (T) + 1, NB) SB                                     \
  LDB(b2x, (T), 2, 0) LDB(b2y, (T), 2, 1) SB                                     \
  KSTEP((BA), b0x, b0y)                                                          \
  STG(2, (T) + 1, NB) STG(3, (T) + 1, NB) SB                                     \
  LDB(b3x, (T), 3, 0) LDB(b3y, (T), 3, 1) SB                                     \
  KSTEP((BA) + 4096, b1x, b1y)                                                   \
  LDB(b0x, (T) + 1, 0, 0) LDB(b0y, (T) + 1, 0, 1) SB                             \
  KSTEP((BA) + 8192, b2x, b2y)                                                   \
  LDB(b1x, (T) + 1, 1, 0) LDB(b1y, (T) + 1, 1, 1) SB                             \
  KSTEP((BA) + 12288, b3x, b3y)                                                  \
  asm volatile("s_waitcnt vmcnt(6)" ::: "memory");                               \
  SB                                                                             \
  __builtin_amdgcn_s_barrier();                                                  \
  SB

  // ---- prologue: stage tile 0 A, prefetch B(0,s0),B(0,s1); gate; barrier
  STG(0, 0, lds_raw) STG(1, 0, lds_raw) STG(2, 0, lds_raw) STG(3, 0, lds_raw) SB
  LDB(b0x, 0, 0, 0) LDB(b0y, 0, 0, 1) LDB(b1x, 0, 1, 0) LDB(b1y, 0, 1, 1) SB
  asm volatile("s_waitcnt vmcnt(4)" ::: "memory");
  SB
  __builtin_amdgcn_s_barrier();
  SB

#pragma unroll 1
  for (int t = 0; t < NKT; t += 2) {
    TILE(t, bA0, lds_raw + 32768)
    TILE(t + 1, bA1, lds_raw)
  }
#undef TILE
#undef KSTEP
#undef LDB
#undef STG
#undef SB

  // ---- epilogue.  32x32 C/D layout: col = lane&31, row = (r&3)+8*(r>>2)+4*(lane>>5)
  const int rbase = arow0 + wr * 128 + ((lane >> 5) << 2);
  const int cbase = brow0 + wc * 64 + (lane & 31);

  if constexpr (MODE == 1) {
    // packed H write: element (n,c) -> tile (n>>8, c>>6), A-layout within
    char* __restrict__ Hc = (char*)Cout;
    const int kexp = brow0 >> 10;  // expert is block-uniform (256 | 1024)
    float bv[2] = {bias[cbase], bias[cbase + 32]};
    size_t cpart[2];
#pragma unroll
    for (int nj = 0; nj < 2; ++nj) {
      int c = cbase + nj * 32;
      cpart[nj] = (size_t)(c >> 6) * 32768 + ((c >> 4) & 3) * 4096
                + ((c >> 3) & 1) * 512 + (c & 7) * 2;
    }
#pragma unroll
    for (int mi = 0; mi < 4; ++mi)
#pragma unroll
      for (int r = 0; r < 16; ++r) {
        int n = rbase + mi * 32 + (r & 3) + 8 * (r >> 2);
        float wn4 = wgt[(size_t)n * KEXP + kexp];
        size_t npart = (size_t)(n >> 8) * (NKT * 32768) + ((n >> 7) & 1) * 16384
                     + ((n >> 5) & 3) * 1024 + (n & 31) * 16;
#pragma unroll
        for (int nj = 0; nj < 2; ++nj) {
          float x = acc[mi][nj][r] + bv[nj];
          float g = 0.5f * x * (1.f + erff(x * 0.70710678118654752f));  // exact GELU
          *(bf16_t*)(Hc + npart + cpart[nj]) = (bf16_t)(g * wn4);
        }
      }
  } else {
    float* __restrict__ O = (float*)Cout;
    float bc0[KEXP], bc1[KEXP];
#pragma unroll
    for (int k = 0; k < KEXP; ++k) {
      bc0[k] = bias[(size_t)k * NCOLS + cbase];
      bc1[k] = bias[(size_t)k * NCOLS + cbase + 32];
    }
#pragma unroll
    for (int mi = 0; mi < 4; ++mi)
#pragma unroll
      for (int r = 0; r < 16; ++r) {
        int n = rbase + mi * 32 + (r & 3) + 8 * (r >> 2);
        const float4* wp = (const float4*)(wgt + (size_t)n * KEXP);
        float4 wa = wp[0], wb = wp[1];
        float w8[KEXP] = {wa.x, wa.y, wa.z, wa.w, wb.x, wb.y, wb.z, wb.w};
        float s0 = 0.f, s1 = 0.f;
#pragma unroll
        for (int k = 0; k < KEXP; ++k) { s0 += w8[k] * bc0[k]; s1 += w8[k] * bc1[k]; }
        O[(size_t)n * NCOLS + cbase]      = acc[mi][0][r] + s0;
        O[(size_t)n * NCOLS + cbase + 32] = acc[mi][1][r] + s1;
      }
  }
}

extern "C" void kernel_launch(void* const* d_in, const int* in_sizes, int n_in,
                              void* d_out, int out_size, void* d_ws, size_t ws_size,
                              hipStream_t stream) {
  const float* h_anchor = (const float*)d_in[0];
  const float* h_mask   = (const float*)d_in[1];
  const float* Wr       = (const float*)d_in[2];
  const float* br       = (const float*)d_in[3];
  const float* W1       = (const float*)d_in[4];
  const float* b1       = (const float*)d_in[5];
  const float* W2       = (const float*)d_in[6];
  const float* b2       = (const float*)d_in[7];
  float* out = (float*)d_out;

  char* ws = (char*)d_ws;
  bf16_t* Apk  = (bf16_t*)(ws);                       // packed A    128 MB
  bf16_t* B1pk = (bf16_t*)(ws + ((size_t)128 << 20)); // packed W1   128 MB
  bf16_t* B2pk = (bf16_t*)(ws + ((size_t)256 << 20)); // packed W2    64 MB
  bf16_t* Hpk  = (bf16_t*)(ws + ((size_t)320 << 20)); // packed H1s  128 MB
  float*  wgt  = (float*) (ws + ((size_t)448 << 20)); // [8192][8]   256 KB

  routing_kernel<<<N_ROWS, 256, 0, stream>>>(h_mask, Wr, br, wgt);
  pack_cond_kernel<<<32 * 128, 256, 0, stream>>>(h_anchor, h_mask, Apk);
  pack_w1_kernel<<<32 * 128, 256, 0, stream>>>(W1, B1pk);
  pack_w2_kernel<<<16 * 128, 256, 0, stream>>>(W2, B2pk);

  gemm256_kernel<1, 8192><<<(N_ROWS / 256) * (KD / 256), 512, 0, stream>>>(
      Apk, B1pk, (void*)Hpk, b1, wgt);
  gemm256_kernel<2, 4096><<<(N_ROWS / 256) * (DDIM / 256), 512, 0, stream>>>(
      Hpk, B2pk, (void*)out, b2, wgt);
}

// Round 13
// 1610.549 us; speedup vs baseline: 1.1600x; 1.1600x over previous
//
#include <hip/hip_runtime.h>
#include <hip/hip_bf16.h>
#include <math.h>

typedef __bf16 bf16_t;
typedef __bf16 bf16x4 __attribute__((ext_vector_type(4)));
typedef __bf16 bf16x8 __attribute__((ext_vector_type(8)));
typedef float  f32x4  __attribute__((ext_vector_type(4)));

#define AS1 __attribute__((address_space(1)))
#define AS3 __attribute__((address_space(3)))

__device__ __forceinline__ void gload_lds16(const bf16_t* g, char* l) {
  __builtin_amdgcn_global_load_lds((const AS1 void*)g, (AS3 void*)l, 16, 0, 0);
}

static constexpr int N_ROWS = 8192;
static constexpr int DDIM   = 4096;
static constexpr int KEXP   = 8;
static constexpr int FHID   = 1024;
static constexpr int KD     = 8192;    // inner dim of both GEMMs (2D and K*F)
static constexpr int NKT64  = KD / 64; // 128 packed 64-k tiles
static constexpr int NKT32  = KD / 32; // 256 GEMM k-steps

// ================= packed fragment-major tile format (r10, verified) =================
// Per (256-row block, 64-k tile): 32 KB contiguous.
// A: (R>>7)*16384 + ((k>>4)&3)*4096 + ((R>>5)&3)*1024 + ((k>>3)&1)*512 + (R&31)*16 + (k&7)*2
// B: ((k>>4)&3)*8192 + ((C>>5)&7)*1024 + ((k>>3)&1)*512 + (C&31)*16 + (k&7)*2

// ---------------- routing: weights = softmax(h_mask @ Wr^T + br) ----------------
__global__ __launch_bounds__(256)
void routing_kernel(const float* __restrict__ hm, const float* __restrict__ Wr,
                    const float* __restrict__ br, float* __restrict__ wgt) {
  const int n = blockIdx.x;
  const int t = threadIdx.x;
  const int wid = t >> 6;
  const float4* row = (const float4*)(hm + (size_t)n * DDIM);
  float4 x[4];
#pragma unroll
  for (int j = 0; j < 4; ++j) x[j] = row[t + j * 256];
  __shared__ float red[KEXP][4];
  float part[KEXP];
#pragma unroll
  for (int k = 0; k < KEXP; ++k) {
    const float4* wr = (const float4*)(Wr + (size_t)k * DDIM);
    float s = 0.f;
#pragma unroll
    for (int j = 0; j < 4; ++j) {
      float4 w4 = wr[t + j * 256];
      s += x[j].x * w4.x + x[j].y * w4.y + x[j].z * w4.z + x[j].w * w4.w;
    }
#pragma unroll
    for (int off = 32; off > 0; off >>= 1) s += __shfl_down(s, off);
    part[k] = s;
  }
  if ((t & 63) == 0) {
#pragma unroll
    for (int k = 0; k < KEXP; ++k) red[k][wid] = part[k];
  }
  __syncthreads();
  if (t == 0) {
    float lg[KEXP];
    float mx = -1e30f;
#pragma unroll
    for (int k = 0; k < KEXP; ++k) {
      lg[k] = red[k][0] + red[k][1] + red[k][2] + red[k][3] + br[k];
      mx = fmaxf(mx, lg[k]);
    }
    float sum = 0.f;
#pragma unroll
    for (int k = 0; k < KEXP; ++k) { lg[k] = expf(lg[k] - mx); sum += lg[k]; }
    float inv = 1.f / sum;
#pragma unroll
    for (int k = 0; k < KEXP; ++k) wgt[(size_t)n * KEXP + k] = lg[k] * inv;
  }
}

// ---------------- pack kernels: fp32 source -> bf16 packed tiles (r10) ----------------
__device__ __forceinline__ bf16x4 cvt4(float4 v) {
  bf16x4 o;
  o[0] = (bf16_t)v.x; o[1] = (bf16_t)v.y; o[2] = (bf16_t)v.z; o[3] = (bf16_t)v.w;
  return o;
}

__global__ __launch_bounds__(256)
void pack_cond_kernel(const float* __restrict__ ha, const float* __restrict__ hm,
                      bf16_t* __restrict__ Apk) {
  const int bm = blockIdx.x >> 7, t = blockIdx.x & 127;
  const int tid = threadIdx.x;
  const float* src = (t < 64) ? ha : hm;
  const int cb = (t & 63) * 64;
  __shared__ char pb[32768];
#pragma unroll
  for (int i = 0; i < 16; ++i) {
    int u = i * 256 + tid;
    int r = u >> 4, c = (u & 15) * 4;
    float4 v = *(const float4*)(src + (size_t)(bm * 256 + r) * DDIM + cb + c);
    int off = ((r >> 7) & 1) * 16384 + ((c >> 4) & 3) * 4096 + ((r >> 5) & 3) * 1024
            + ((c >> 3) & 1) * 512 + (r & 31) * 16 + (c & 7) * 2;
    *(bf16x4*)(pb + off) = cvt4(v);
  }
  __syncthreads();
  char* dst = (char*)Apk + (size_t)blockIdx.x * 32768;
#pragma unroll
  for (int i = 0; i < 8; ++i) {
    int off = i * 4096 + tid * 16;
    *(float4*)(dst + off) = *(const float4*)(pb + off);
  }
}

__global__ __launch_bounds__(256)
void pack_w1_kernel(const float* __restrict__ W1, bf16_t* __restrict__ Bpk) {
  const int bn = blockIdx.x >> 7, t = blockIdx.x & 127;
  const int tid = threadIdx.x;
  __shared__ char pb[32768];
#pragma unroll
  for (int i = 0; i < 16; ++i) {
    int u = i * 256 + tid;
    int r = u >> 4, c = (u & 15) * 4;
    float4 v = *(const float4*)(W1 + (size_t)(bn * 256 + r) * KD + t * 64 + c);
    int off = ((c >> 4) & 3) * 8192 + ((r >> 5) & 7) * 1024
            + ((c >> 3) & 1) * 512 + (r & 31) * 16 + (c & 7) * 2;
    *(bf16x4*)(pb + off) = cvt4(v);
  }
  __syncthreads();
  char* dst = (char*)Bpk + (size_t)blockIdx.x * 32768;
#pragma unroll
  for (int i = 0; i < 8; ++i) {
    int off = i * 4096 + tid * 16;
    *(float4*)(dst + off) = *(const float4*)(pb + off);
  }
}

__global__ __launch_bounds__(256)
void pack_w2_kernel(const float* __restrict__ W2, bf16_t* __restrict__ Bpk) {
  const int bn = blockIdx.x >> 7, t = blockIdx.x & 127;
  const int tid = threadIdx.x;
  const int ke = t >> 4, f0 = (t & 15) * 64;
  __shared__ char pb[32768];
#pragma unroll
  for (int i = 0; i < 16; ++i) {
    int u = i * 256 + tid;
    int r = u >> 4, c = (u & 15) * 4;
    float4 v = *(const float4*)(W2 + ((size_t)ke * DDIM + bn * 256 + r) * FHID + f0 + c);
    int off = ((c >> 4) & 3) * 8192 + ((r >> 5) & 7) * 1024
            + ((c >> 3) & 1) * 512 + (r & 31) * 16 + (c & 7) * 2;
    *(bf16x4*)(pb + off) = cvt4(v);
  }
  __syncthreads();
  char* dst = (char*)Bpk + (size_t)blockIdx.x * 32768;
#pragma unroll
  for (int i = 0; i < 8; ++i) {
    int off = i * 4096 + tid * 16;
    *(float4*)(dst + off) = *(const float4*)(pb + off);
  }
}

// ---------------- GEMM v13: 256x128 tile, 2 blocks/CU, de-lockstep via TLP --------
// BK=32, LDS = 3-buffer ring x 24KB (A 16KB + B 8KB) = 72KB -> 2 blocks co-resident
// per CU (144KB LDS, 16 waves, 128 VGPR cap via __launch_bounds__(512,4)). The two
// blocks have INDEPENDENT barriers: while one block's waves drain reads, the other's
// feed the MFMA pipe (m114 mechanism) - attacks the 55% lockstep wall directly.
// 8 waves of 64x64 (acc[4][4] f32x4 = 64 VGPR), 16x16x32 MFMA.
// Per K-tile body: stage(t+2) 3x1KB/wave -> reads a0..3,b0..3 (pinned) ->
// lgkm countdown(3/2/1/0) x 4-MFMA clusters -> vmcnt(3) -> ONE barrier.
// Safety: vmcnt(3) retires t+1's stages pre-barrier (cross-wave publish); stages(t+2)
// target buffer (t-1)%3 whose reads drained (lgkm0) before the prior barrier; modular
// wrap keeps counts uniform incl. tail (round-3 lesson).
// Reads from r10 packed format re-addressed for BK=32: each frag read = 4 disjoint
// 256B runs (lanes 0-15/16-31/32-47/48-63) -> conflict-free (bank audit).
// MODE 1: +b1, exact GELU, *w[n][expert], store bf16 PACKED (Hpk = GEMM2's A)
// MODE 2: + sum_k w[n][k]*b2[k][col], store fp32 row-major (out)
template <int MODE, int NCOLS>
__global__ __launch_bounds__(512, 4)
void gemm_kernel(const bf16_t* __restrict__ Apk, const bf16_t* __restrict__ Bpk,
                 void* __restrict__ Cout, const float* __restrict__ bias,
                 const float* __restrict__ wgt) {
  __shared__ char lds[3 * 24576];        // 72 KB

  const int tid  = threadIdx.x;
  const int wid  = tid >> 6;             // 0..7
  const int lane = tid & 63;
  const int wr   = wid >> 1;             // 0..3  (M quarter, 64 rows)
  const int wc   = wid & 1;              // 0..1  (N half, 64 cols)

  // ---- 2-D concurrency-window block remap (16bm x 16bn window, 4x8 per XCD)
  constexpr int NBN    = NCOLS / 128;    // 64 (GEMM1) or 32 (GEMM2)
  constexpr int NWIN_N = NBN / 16;       // 4 or 2
  const int bid = blockIdx.x;
  const int w   = bid >> 8;
  const int sl  = bid & 255;
  const int xcd = sl & 7;
  const int cu  = sl >> 3;
  const int wm  = w / NWIN_N, wn = w % NWIN_N;
  const int bm  = wm * 16 + ((xcd >> 1) << 2) + (cu & 3);
  const int bn  = wn * 16 + ((xcd & 1) << 3) + (cu >> 2);
  const int arow0 = bm * 256;
  const int bcol0 = bn * 128;

  // ---- staging: 24 x 1KB pieces per K-tile (16 A + 8 B); wave stages A{2w,2w+1}, B{w}
  const char* Abase = (const char*)Apk + (size_t)bm * NKT64 * 32768;
  const char* Bbase = (const char*)Bpk + (size_t)(bn >> 1) * NKT64 * 32768;
  const int pA0 = 2 * wid, pA1 = 2 * wid + 1, qB = wid;
  // A piece p: Rhalf=p>>3, k16=(p>>2)&1, rg=p&3
  const int a0s = (pA0 >> 3) * 16384 + ((pA0 >> 2) & 1) * 4096 + (pA0 & 3) * 1024;
  const int a1s = (pA1 >> 3) * 16384 + ((pA1 >> 2) & 1) * 4096 + (pA1 & 3) * 1024;
  const int a0d = (pA0 >> 3) * 8192 + ((pA0 >> 2) & 1) * 4096 + (pA0 & 3) * 1024;
  const int a1d = (pA1 >> 3) * 8192 + ((pA1 >> 2) & 1) * 4096 + (pA1 & 3) * 1024;
  // B piece q: k16=q>>2, cg=q&3; source col-half = bn&1
  const int bqs = (qB >> 2) * 8192 + ((bn & 1) * 4 + (qB & 3)) * 1024;
  const int bqd = 16384 + (qB >> 2) * 4096 + (qB & 3) * 1024;

  // ---- read offsets (per-lane, conflict-free: 4 x 256B runs)
  const int lpart = (lane & 15) * 16 + ((lane >> 4) & 1) * 512 + (lane >> 5) * 4096;
  int aoff[4], boff[4];
#pragma unroll
  for (int mi = 0; mi < 4; ++mi)
    aoff[mi] = (wr >> 1) * 8192 + ((wr & 1) * 2 + (mi >> 1)) * 1024 + (mi & 1) * 256 + lpart;
#pragma unroll
  for (int nj = 0; nj < 4; ++nj)
    boff[nj] = 16384 + (wc * 2 + (nj >> 1)) * 1024 + (nj & 1) * 256 + lpart;

  f32x4 acc[4][4];
  f32x4 zero = {0.f, 0.f, 0.f, 0.f};
#pragma unroll
  for (int mi = 0; mi < 4; ++mi)
#pragma unroll
    for (int nj = 0; nj < 4; ++nj) acc[mi][nj] = zero;

#define SB __builtin_amdgcn_sched_barrier(0);
#define STG3(KT, BUF)                                                            \
  {                                                                              \
    const int kt_ = (KT) & (NKT32 - 1);                                          \
    const size_t t64 = (size_t)(kt_ >> 1) * 32768;                               \
    const int klo = (kt_ & 1) * 2;                                               \
    gload_lds16((const bf16_t*)(Abase + t64 + a0s + klo * 4096 + lane * 16),     \
                (BUF) + a0d);                                                    \
    gload_lds16((const bf16_t*)(Abase + t64 + a1s + klo * 4096 + lane * 16),     \
                (BUF) + a1d);                                                    \
    gload_lds16((const bf16_t*)(Bbase + t64 + bqs + klo * 8192 + lane * 16),     \
                (BUF) + bqd);                                                    \
  }

  // ---- prologue: stage tile 0 -> buf0, tile 1 -> buf1; retire t0; barrier
  STG3(0, lds) STG3(1, lds + 24576) SB
  asm volatile("s_waitcnt vmcnt(3)" ::: "memory");
  SB
  __builtin_amdgcn_s_barrier();
  SB

  char* rb = lds;                 // read buffer  (t   % 3)
  char* mb = lds + 24576;         // next read    (t+1 % 3)
  char* sb = lds + 49152;         // stage target (t+2 % 3)

#pragma unroll 1
  for (int t = 0; t < NKT32; ++t) {
    STG3(t + 2, sb) SB
    bf16x8 a0, a1, a2, a3, b0, b1, b2, b3;
    a0 = *(const bf16x8*)(rb + aoff[0]); SB
    a1 = *(const bf16x8*)(rb + aoff[1]); SB
    a2 = *(const bf16x8*)(rb + aoff[2]); SB
    a3 = *(const bf16x8*)(rb + aoff[3]); SB
    b0 = *(const bf16x8*)(rb + boff[0]); SB
    b1 = *(const bf16x8*)(rb + boff[1]); SB
    b2 = *(const bf16x8*)(rb + boff[2]); SB
    b3 = *(const bf16x8*)(rb + boff[3]); SB
    __builtin_amdgcn_s_setprio(1);
    asm volatile("s_waitcnt lgkmcnt(3)" ::: "memory"); SB
    acc[0][0] = __builtin_amdgcn_mfma_f32_16x16x32_bf16(a0, b0, acc[0][0], 0, 0, 0);
    acc[1][0] = __builtin_amdgcn_mfma_f32_16x16x32_bf16(a1, b0, acc[1][0], 0, 0, 0);
    acc[2][0] = __builtin_amdgcn_mfma_f32_16x16x32_bf16(a2, b0, acc[2][0], 0, 0, 0);
    acc[3][0] = __builtin_amdgcn_mfma_f32_16x16x32_bf16(a3, b0, acc[3][0], 0, 0, 0);
    SB
    asm volatile("s_waitcnt lgkmcnt(2)" ::: "memory"); SB
    acc[0][1] = __builtin_amdgcn_mfma_f32_16x16x32_bf16(a0, b1, acc[0][1], 0, 0, 0);
    acc[1][1] = __builtin_amdgcn_mfma_f32_16x16x32_bf16(a1, b1, acc[1][1], 0, 0, 0);
    acc[2][1] = __builtin_amdgcn_mfma_f32_16x16x32_bf16(a2, b1, acc[2][1], 0, 0, 0);
    acc[3][1] = __builtin_amdgcn_mfma_f32_16x16x32_bf16(a3, b1, acc[3][1], 0, 0, 0);
    SB
    asm volatile("s_waitcnt lgkmcnt(1)" ::: "memory"); SB
    acc[0][2] = __builtin_amdgcn_mfma_f32_16x16x32_bf16(a0, b2, acc[0][2], 0, 0, 0);
    acc[1][2] = __builtin_amdgcn_mfma_f32_16x16x32_bf16(a1, b2, acc[1][2], 0, 0, 0);
    acc[2][2] = __builtin_amdgcn_mfma_f32_16x16x32_bf16(a2, b2, acc[2][2], 0, 0, 0);
    acc[3][2] = __builtin_amdgcn_mfma_f32_16x16x32_bf16(a3, b2, acc[3][2], 0, 0, 0);
    SB
    asm volatile("s_waitcnt lgkmcnt(0)" ::: "memory"); SB
    acc[0][3] = __builtin_amdgcn_mfma_f32_16x16x32_bf16(a0, b3, acc[0][3], 0, 0, 0);
    acc[1][3] = __builtin_amdgcn_mfma_f32_16x16x32_bf16(a1, b3, acc[1][3], 0, 0, 0);
    acc[2][3] = __builtin_amdgcn_mfma_f32_16x16x32_bf16(a2, b3, acc[2][3], 0, 0, 0);
    acc[3][3] = __builtin_amdgcn_mfma_f32_16x16x32_bf16(a3, b3, acc[3][3], 0, 0, 0);
    SB
    __builtin_amdgcn_s_setprio(0);
    asm volatile("s_waitcnt vmcnt(3)" ::: "memory");  // t+1's stages retired (publish)
    SB
    __builtin_amdgcn_s_barrier();
    SB
    char* tmp = rb; rb = mb; mb = sb; sb = tmp;
  }
#undef STG3
#undef SB

  // ---- epilogue.  16x16 C/D layout: col = lane&15, row = (lane>>4)*4 + r  [m89/m91]
  const int rbase = arow0 + wr * 64 + ((lane >> 4) << 2);
  const int cbase = bcol0 + wc * 64 + (lane & 15);

  if constexpr (MODE == 1) {
    // packed H write (r10 A-format): H has 8192 rows x 8192 k
    char* __restrict__ Hc = (char*)Cout;
    const int kexp = bcol0 >> 10;  // expert is block-uniform (128 | 1024)
    float bv[4];
    size_t cpart[4];
#pragma unroll
    for (int nj = 0; nj < 4; ++nj) {
      int c = cbase + nj * 16;
      bv[nj] = bias[c];
      cpart[nj] = (size_t)(c >> 6) * 32768 + ((c >> 4) & 3) * 4096
                + ((c >> 3) & 1) * 512 + (c & 7) * 2;
    }
#pragma unroll
    for (int mi = 0; mi < 4; ++mi)
#pragma unroll
      for (int r = 0; r < 4; ++r) {
        int n = rbase + mi * 16 + r;
        float wn4 = wgt[(size_t)n * KEXP + kexp];
        size_t npart = (size_t)(n >> 8) * (NKT64 * 32768) + ((n >> 7) & 1) * 16384
                     + ((n >> 5) & 3) * 1024 + (n & 31) * 16;
#pragma unroll
        for (int nj = 0; nj < 4; ++nj) {
          float x = acc[mi][nj][r] + bv[nj];
          float g = 0.5f * x * (1.f + erff(x * 0.70710678118654752f));  // exact GELU
          *(bf16_t*)(Hc + npart + cpart[nj]) = (bf16_t)(g * wn4);
        }
      }
  } else {
    float* __restrict__ O = (float*)Cout;
    float bc[4][KEXP];
#pragma unroll
    for (int nj = 0; nj < 4; ++nj)
#pragma unroll
      for (int k = 0; k < KEXP; ++k)
        bc[nj][k] = bias[(size_t)k * NCOLS + cbase + nj * 16];
#pragma unroll
    for (int mi = 0; mi < 4; ++mi)
#pragma unroll
      for (int r = 0; r < 4; ++r) {
        int n = rbase + mi * 16 + r;
        const float4* wp = (const float4*)(wgt + (size_t)n * KEXP);
        float4 wa = wp[0], wb = wp[1];
        float w8[KEXP] = {wa.x, wa.y, wa.z, wa.w, wb.x, wb.y, wb.z, wb.w};
#pragma unroll
        for (int nj = 0; nj < 4; ++nj) {
          float s = 0.f;
#pragma unroll
          for (int k = 0; k < KEXP; ++k) s += w8[k] * bc[nj][k];
          O[(size_t)n * NCOLS + cbase + nj * 16] = acc[mi][nj][r] + s;
        }
      }
  }
}

extern "C" void kernel_launch(void* const* d_in, const int* in_sizes, int n_in,
                              void* d_out, int out_size, void* d_ws, size_t ws_size,
                              hipStream_t stream) {
  const float* h_anchor = (const float*)d_in[0];
  const float* h_mask   = (const float*)d_in[1];
  const float* Wr       = (const float*)d_in[2];
  const float* br       = (const float*)d_in[3];
  const float* W1       = (const float*)d_in[4];
  const float* b1       = (const float*)d_in[5];
  const float* W2       = (const float*)d_in[6];
  const float* b2       = (const float*)d_in[7];
  float* out = (float*)d_out;

  char* ws = (char*)d_ws;
  bf16_t* Apk  = (bf16_t*)(ws);                       // packed A    128 MB
  bf16_t* B1pk = (bf16_t*)(ws + ((size_t)128 << 20)); // packed W1   128 MB
  bf16_t* B2pk = (bf16_t*)(ws + ((size_t)256 << 20)); // packed W2    64 MB
  bf16_t* Hpk  = (bf16_t*)(ws + ((size_t)320 << 20)); // packed H1s  128 MB
  float*  wgt  = (float*) (ws + ((size_t)448 << 20)); // [8192][8]   256 KB

  routing_kernel<<<N_ROWS, 256, 0, stream>>>(h_mask, Wr, br, wgt);
  pack_cond_kernel<<<32 * 128, 256, 0, stream>>>(h_anchor, h_mask, Apk);
  pack_w1_kernel<<<32 * 128, 256, 0, stream>>>(W1, B1pk);
  pack_w2_kernel<<<16 * 128, 256, 0, stream>>>(W2, B2pk);

  gemm_kernel<1, 8192><<<(N_ROWS / 256) * (KD / 128), 512, 0, stream>>>(
      Apk, B1pk, (void*)Hpk, b1, wgt);
  gemm_kernel<2, 4096><<<(N_ROWS / 256) * (DDIM / 128), 512, 0, stream>>>(
      Hpk, B2pk, (void*)out, b2, wgt);
}